// Round 2
// baseline (5757.245 us; speedup 1.0000x reference)
//
#include <hip/hip_runtime.h>
#include <math.h>

#define B_   128
#define L_   401
#define DM   192
#define DI   384
#define DSTATE 16
#define DTR  12

// ---------------- embed: x[b,l,d] = flat @ pe_w^T + pe_b + pos_embed ----------------
__global__ void embed_kernel(const float* __restrict__ imgs,
                             const float* __restrict__ pe_w,
                             const float* __restrict__ pe_b,
                             const float* __restrict__ cls_token,
                             const float* __restrict__ pos_embed,
                             float* __restrict__ x)
{
    int row = blockIdx.x;          // blocal*L_ + l
    int l = row % L_;
    int b = row / L_;              // chunk-local; imgs pre-offset
    int d = threadIdx.x;           // 192 threads
    float v;
    if (l < 400) {
        const float* f = imgs + (size_t)b * 1600 + (size_t)l * 4;
        const float* pw = pe_w + d * 4;
        v = pe_b[d];
        v = fmaf(f[0], pw[0], v);
        v = fmaf(f[1], pw[1], v);
        v = fmaf(f[2], pw[2], v);
        v = fmaf(f[3], pw[3], v);
        v += pos_embed[l * DM + d];
    } else {
        v = cls_token[d] + pos_embed[400 * DM + d];
    }
    x[(size_t)row * DM + d] = v;
}

// ---------------- rms norm + residual update ----------------
__global__ __launch_bounds__(256) void rms_kernel(
    const float* hidden, float* residual, float* normed,
    const float* __restrict__ w, int add, int nrows)
{
    int wv   = threadIdx.x >> 6;
    int lane = threadIdx.x & 63;
    int row  = blockIdx.x * 4 + wv;
    if (row >= nrows) return;
    const float* hr = hidden + (size_t)row * DM;
    float* rr = residual + (size_t)row * DM;
    float x0 = hr[lane], x1 = hr[lane + 64], x2 = hr[lane + 128];
    if (add) { x0 += rr[lane]; x1 += rr[lane + 64]; x2 += rr[lane + 128]; }
    rr[lane] = x0; rr[lane + 64] = x1; rr[lane + 128] = x2;
    float ss = x0 * x0 + x1 * x1 + x2 * x2;
    #pragma unroll
    for (int off = 32; off > 0; off >>= 1) ss += __shfl_down(ss, off);
    ss = __shfl(ss, 0);
    float scale = rsqrtf(ss / (float)DM + 1e-5f);
    float* nr = normed + (size_t)row * DM;
    nr[lane]       = x0 * scale * w[lane];
    nr[lane + 64]  = x1 * scale * w[lane + 64];
    nr[lane + 128] = x2 * scale * w[lane + 128];
}

// ---------------- generic fp32 GEMM: C[M,N] = A[M,K] * W[N,K]^T (+bias)(+act) ------
// act: 0 = none, 1 = softplus
#define BM 64
#define BN 64
#define BK 16
__global__ __launch_bounds__(256) void gemm_atb(
    const float* __restrict__ A, int lda,
    const float* __restrict__ W, int ldw,
    float* __restrict__ C, int ldc,
    const float* __restrict__ bias,
    int M, int N, int K, int act)
{
    __shared__ __align__(16) float As[BK][BM + 4];
    __shared__ __align__(16) float Ws[BK][BN + 4];
    int bm = blockIdx.x * BM;
    int bn = blockIdx.y * BN;
    int t = threadIdx.x;
    int tr = (t >> 4) * 4;
    int tc = (t & 15) * 4;
    float acc[4][4] = {};
    for (int k0 = 0; k0 < K; k0 += BK) {
        #pragma unroll
        for (int e = 0; e < 4; ++e) {
            int i  = t + e * 256;      // 0..1023
            int m  = i >> 4;
            int kk = i & 15;
            int gk = k0 + kk;
            int gm = bm + m;
            As[kk][m] = (gm < M && gk < K) ? A[(size_t)gm * lda + gk] : 0.f;
            int gn = bn + m;
            Ws[kk][m] = (gn < N && gk < K) ? W[(size_t)gn * ldw + gk] : 0.f;
        }
        __syncthreads();
        #pragma unroll
        for (int kk = 0; kk < BK; ++kk) {
            float a[4], b[4];
            *(float4*)a = *(const float4*)&As[kk][tr];
            *(float4*)b = *(const float4*)&Ws[kk][tc];
            #pragma unroll
            for (int i2 = 0; i2 < 4; ++i2)
                #pragma unroll
                for (int j2 = 0; j2 < 4; ++j2)
                    acc[i2][j2] = fmaf(a[i2], b[j2], acc[i2][j2]);
        }
        __syncthreads();
    }
    #pragma unroll
    for (int i2 = 0; i2 < 4; ++i2) {
        int gm = bm + tr + i2;
        if (gm >= M) continue;
        #pragma unroll
        for (int j2 = 0; j2 < 4; ++j2) {
            int gn = bn + tc + j2;
            if (gn >= N) continue;
            float v = acc[i2][j2];
            if (bias) v += bias[gn];
            if (act == 1) v = fmaxf(v, 0.f) + log1pf(expf(-fabsf(v)));   // softplus
            C[(size_t)gm * ldc + gn] = v;
        }
    }
}

// ---------------- causal depthwise conv (width 4) + silu ----------------
__global__ __launch_bounds__(256) void conv_silu_kernel(
    const float* __restrict__ xz, const float* __restrict__ cw,
    const float* __restrict__ cb, float* __restrict__ xc, int total)
{
    int idx = blockIdx.x * 256 + threadIdx.x;
    if (idx >= total) return;
    int d  = idx % DI;
    int bl = idx / DI;     // blocal*L_ + l
    int l  = bl % L_;
    float acc = cb[d];
    const float* cwd = cw + d * 4;
    #pragma unroll
    for (int k = 0; k < 4; ++k) {
        int ls = l + k - 3;
        if (ls >= 0)
            acc = fmaf(cwd[k], xz[(size_t)(bl - l + ls) * (2 * DI) + d], acc);
    }
    float sig = 1.f / (1.f + __expf(-acc));
    xc[idx] = acc * sig;
}

// ---------------- selective scan (sequential over L, thread per (b,d)) ----------------
// xzdt: row stride 768. cols [0,384) hold dt on input, y*silu(z) on output.
//       cols [384,768) hold z.
__global__ __launch_bounds__(64) void scan_kernel(
    float* xzdt,
    const float* __restrict__ xc,
    const float* __restrict__ dbl,
    const float* __restrict__ A_log,
    const float* __restrict__ Dp)
{
    int b    = blockIdx.x / (DI / 64);   // chunk-local
    int dblk = blockIdx.x % (DI / 64);
    int d    = dblk * 64 + threadIdx.x;
    float Areg[DSTATE];
    #pragma unroll
    for (int s = 0; s < DSTATE; ++s) Areg[s] = -expf(A_log[d * DSTATE + s]);
    float Dval = Dp[d];
    float h[DSTATE];
    #pragma unroll
    for (int s = 0; s < DSTATE; ++s) h[s] = 0.f;

    size_t base = (size_t)b * L_;
    float dtv = xzdt[(base + 0) * (2 * DI) + d];
    float xcv = xc  [(base + 0) * DI + d];
    float zv  = xzdt[(base + 0) * (2 * DI) + DI + d];
    for (int l = 0; l < L_; ++l) {
        const float* bc = dbl + (base + l) * 44 + DTR;   // wave-uniform -> scalar loads
        float dtn = 0.f, xcn = 0.f, zn = 0.f;
        if (l + 1 < L_) {
            dtn = xzdt[(base + l + 1) * (2 * DI) + d];
            xcn = xc  [(base + l + 1) * DI + d];
            zn  = xzdt[(base + l + 1) * (2 * DI) + DI + d];
        }
        float coef = dtv * xcv;
        float y = 0.f;
        #pragma unroll
        for (int s = 0; s < DSTATE; ++s) {
            float dA = __expf(dtv * Areg[s]);
            h[s] = fmaf(h[s], dA, coef * bc[s]);
            y = fmaf(h[s], bc[DSTATE + s], y);
        }
        float yv  = fmaf(Dval, xcv, y);
        float sig = 1.f / (1.f + __expf(-zv));
        xzdt[(base + l) * (2 * DI) + d] = yv * (zv * sig);
        dtv = dtn; xcv = xcn; zv = zn;
    }
}

// ---------------- final rms on cls row only ----------------
__global__ __launch_bounds__(64) void final_kernel(
    const float* __restrict__ hidden, const float* __restrict__ residual,
    const float* __restrict__ wf, float* __restrict__ v_sem)
{
    int b = blockIdx.x;    // chunk-local; v_sem pre-offset
    int lane = threadIdx.x;
    size_t row = (size_t)b * L_ + 400;
    const float* hr = hidden + row * DM;
    const float* rr = residual + row * DM;
    float x0 = hr[lane] + rr[lane];
    float x1 = hr[lane + 64] + rr[lane + 64];
    float x2 = hr[lane + 128] + rr[lane + 128];
    float ss = x0 * x0 + x1 * x1 + x2 * x2;
    #pragma unroll
    for (int off = 32; off > 0; off >>= 1) ss += __shfl_down(ss, off);
    ss = __shfl(ss, 0);
    float scale = rsqrtf(ss / (float)DM + 1e-5f);
    v_sem[b * DM + lane]       = x0 * scale * wf[lane];
    v_sem[b * DM + lane + 64]  = x1 * scale * wf[lane + 64];
    v_sem[b * DM + lane + 128] = x2 * scale * wf[lane + 128];
}

// ---------------- tiny MLPs + head ----------------
__global__ __launch_bounds__(256) void mlp1_kernel(
    const float* __restrict__ pl, const float* __restrict__ iat,
    const float* __restrict__ w, const float* __restrict__ bias,
    float* __restrict__ out)
{
    int idx = blockIdx.x * 256 + threadIdx.x;
    if (idx >= 128 * 128) return;
    int b = idx / 128, j = idx % 128;
    float acc = bias[j];
    const float* wr = w + j * 200;
    const float* pr = pl + b * 100;
    const float* ir = iat + b * 100;
    for (int k = 0; k < 100; ++k) acc = fmaf(pr[k], wr[k], acc);
    for (int k = 0; k < 100; ++k) acc = fmaf(ir[k], wr[100 + k], acc);
    out[idx] = fmaxf(acc, 0.f);
}

__global__ __launch_bounds__(256) void mlp2_kernel(
    const float* __restrict__ h1, const float* __restrict__ w,
    const float* __restrict__ bias, float* __restrict__ out)
{
    int idx = blockIdx.x * 256 + threadIdx.x;
    if (idx >= 128 * 128) return;
    int b = idx / 128, j = idx % 128;
    float acc = bias[j];
    const float* wr = w + j * 128;
    const float* hr = h1 + b * 128;
    for (int k = 0; k < 128; ++k) acc = fmaf(hr[k], wr[k], acc);
    out[idx] = acc;
}

__global__ __launch_bounds__(256) void head_kernel(
    const float* __restrict__ v_sem, const float* __restrict__ v_stat,
    const float* __restrict__ w, const float* __restrict__ bias,
    float* __restrict__ out)
{
    int idx = blockIdx.x * 256 + threadIdx.x;
    if (idx >= 128 * 20) return;
    int b = idx / 20, o = idx % 20;
    float acc = bias[o];
    const float* wr = w + o * 320;
    const float* vs = v_sem + b * DM;
    const float* vt = v_stat + b * 128;
    for (int k = 0; k < DM; ++k)  acc = fmaf(vs[k], wr[k], acc);
    for (int k = 0; k < 128; ++k) acc = fmaf(vt[k], wr[DM + k], acc);
    out[idx] = acc;
}

extern "C" void kernel_launch(void* const* d_in, const int* in_sizes, int n_in,
                              void* d_out, int out_size, void* d_ws, size_t ws_size,
                              hipStream_t stream)
{
    const float* imgs       = (const float*)d_in[0];
    const float* pl         = (const float*)d_in[1];
    const float* iat        = (const float*)d_in[2];
    const float* pe_w       = (const float*)d_in[3];
    const float* pe_b       = (const float*)d_in[4];
    const float* cls_token  = (const float*)d_in[5];
    const float* pos_embed  = (const float*)d_in[6];
    const float* norm_ws    = (const float*)d_in[7];
    const float* in_proj_ws = (const float*)d_in[8];
    const float* conv_ws    = (const float*)d_in[9];
    const float* conv_bs    = (const float*)d_in[10];
    const float* x_proj_ws  = (const float*)d_in[11];
    const float* dt_proj_ws = (const float*)d_in[12];
    const float* dt_proj_bs = (const float*)d_in[13];
    const float* A_logs     = (const float*)d_in[14];
    const float* Ds         = (const float*)d_in[15];
    const float* out_proj_ws= (const float*)d_in[16];
    const float* norm_f_w   = (const float*)d_in[17];
    const float* mlp1_w     = (const float*)d_in[18];
    const float* mlp1_b     = (const float*)d_in[19];
    const float* mlp2_w     = (const float*)d_in[20];
    const float* mlp2_b     = (const float*)d_in[21];
    const float* head_w     = (const float*)d_in[22];
    const float* head_b     = (const float*)d_in[23];

    float* ws = (float*)d_ws;
    // persistent small buffers (full batch)
    float* v_sem  = ws;                       // 128*192
    float* h1     = v_sem + 128 * DM;         // 128*128
    float* v_stat = h1 + 128 * 128;           // 128*128
    float* chunkbuf = v_stat + 128 * 128;
    size_t small_floats = (size_t)128 * DM + 2 * 128 * 128;

    // per-row floats: hidden(192)+residual(192)+xz(768, dt/y aliased into xi cols)+xc(384)+dbl(44)
    const size_t per_row = DM + DM + 2 * DI + DI + 44;   // 1580
    size_t avail = ws_size / sizeof(float);
    avail = (avail > small_floats) ? (avail - small_floats) : 0;
    int Bc = (int)(avail / (per_row * (size_t)L_));
    if (Bc > B_) Bc = B_;
    if (Bc < 1) Bc = 1;   // below this nothing fits; would need ~2.6 MB

    for (int b0 = 0; b0 < B_; b0 += Bc) {
        int bc = (B_ - b0 < Bc) ? (B_ - b0) : Bc;
        int rows = bc * L_;
        float* hidden   = chunkbuf;
        float* residual = hidden + (size_t)rows * DM;
        float* xz       = residual + (size_t)rows * DM;   // [rows][768]
        float* xc       = xz + (size_t)rows * 2 * DI;
        float* dbl      = xc + (size_t)rows * DI;

        int gm = (rows + BM - 1) / BM;

        embed_kernel<<<rows, DM, 0, stream>>>(imgs + (size_t)b0 * 1600,
                                              pe_w, pe_b, cls_token, pos_embed, hidden);

        for (int i = 0; i < 4; ++i) {
            rms_kernel<<<(rows + 3) / 4, 256, 0, stream>>>(
                hidden, residual, hidden, norm_ws + i * DM, i > 0 ? 1 : 0, rows);
            // in_proj: (rows,192) x (768,192)^T -> xz (rows,768)
            gemm_atb<<<dim3(gm, 12), 256, 0, stream>>>(
                hidden, DM, in_proj_ws + (size_t)i * 2 * DI * DM, DM,
                xz, 2 * DI, nullptr, rows, 2 * DI, DM, 0);
            // conv + silu: xz xi-cols -> xc
            int convTot = rows * DI;
            conv_silu_kernel<<<(convTot + 255) / 256, 256, 0, stream>>>(
                xz, conv_ws + i * DI * 4, conv_bs + i * DI, xc, convTot);
            // x_proj: (rows,384) x (44,384)^T -> dbl (rows,44)
            gemm_atb<<<dim3(gm, 1), 256, 0, stream>>>(
                xc, DI, x_proj_ws + (size_t)i * 44 * DI, DI,
                dbl, 44, nullptr, rows, 44, DI, 0);
            // dt_proj: (rows,12 of 44) x (384,12)^T + bias -> softplus -> xz cols [0,384)
            gemm_atb<<<dim3(gm, 6), 256, 0, stream>>>(
                dbl, 44, dt_proj_ws + (size_t)i * DI * DTR, DTR,
                xz, 2 * DI, dt_proj_bs + i * DI, rows, DI, DTR, 1);
            // scan: dt/y in xz cols [0,384), z in cols [384,768)
            scan_kernel<<<bc * (DI / 64), 64, 0, stream>>>(
                xz, xc, dbl, A_logs + (size_t)i * DI * DSTATE, Ds + i * DI);
            // out_proj: (rows,384 from xz ld 768) x (192,384)^T -> hidden (rows,192)
            gemm_atb<<<dim3(gm, 3), 256, 0, stream>>>(
                xz, 2 * DI, out_proj_ws + (size_t)i * DM * DI, DI,
                hidden, DM, nullptr, rows, DM, DI, 0);
        }

        final_kernel<<<bc, 64, 0, stream>>>(hidden, residual, norm_f_w,
                                            v_sem + (size_t)b0 * DM);
    }

    mlp1_kernel<<<64, 256, 0, stream>>>(pl, iat, mlp1_w, mlp1_b, h1);
    mlp2_kernel<<<64, 256, 0, stream>>>(h1, mlp2_w, mlp2_b, v_stat);
    head_kernel<<<10, 256, 0, stream>>>(v_sem, v_stat, head_w, head_b, (float*)d_out);
}

// Round 3
// 3462.875 us; speedup vs baseline: 1.6626x; 1.6626x over previous
//
#include <hip/hip_runtime.h>
#include <math.h>

#define B_   128
#define L_   401
#define DM   192
#define DI   384
#define DSTATE 16
#define DTR  12
#define DBLD 48      // padded leading dim for dbl (fp32 and bf16)

typedef __attribute__((ext_vector_type(8))) short s8b;   // 8 bf16 in 4 VGPRs
typedef __attribute__((ext_vector_type(4))) float f4;

__device__ __forceinline__ unsigned short f2bf(float x) {
    unsigned int u = __builtin_bit_cast(unsigned int, x);
    unsigned int r = (u + 0x7fffu + ((u >> 16) & 1u)) >> 16;
    return (unsigned short)r;
}

// ---------------- weight fp32 -> bf16 (with column pad) ----------------
__global__ __launch_bounds__(256) void convw_kernel(
    const float* __restrict__ src, unsigned short* __restrict__ dst,
    int rows, int K, int dld)
{
    int total = rows * dld;
    for (int idx = blockIdx.x * 256 + threadIdx.x; idx < total; idx += gridDim.x * 256) {
        int r = idx / dld, j = idx - r * dld;
        dst[idx] = (j < K) ? f2bf(src[r * K + j]) : (unsigned short)0;
    }
}

// ---------------- embed ----------------
__global__ void embed_kernel(const float* __restrict__ imgs,
                             const float* __restrict__ pe_w,
                             const float* __restrict__ pe_b,
                             const float* __restrict__ cls_token,
                             const float* __restrict__ pos_embed,
                             float* __restrict__ x)
{
    int row = blockIdx.x;          // blocal*L_ + l
    int l = row % L_;
    int b = row / L_;
    int d = threadIdx.x;           // 192 threads
    float v;
    if (l < 400) {
        const float* f = imgs + (size_t)b * 1600 + (size_t)l * 4;
        const float* pw = pe_w + d * 4;
        v = pe_b[d];
        v = fmaf(f[0], pw[0], v);
        v = fmaf(f[1], pw[1], v);
        v = fmaf(f[2], pw[2], v);
        v = fmaf(f[3], pw[3], v);
        v += pos_embed[l * DM + d];
    } else {
        v = cls_token[d] + pos_embed[400 * DM + d];
    }
    x[(size_t)row * DM + d] = v;
}

// ---------------- rms norm (+residual), bf16 normed output ----------------
__global__ __launch_bounds__(256) void rms_kernel(
    const float* hidden, float* residual, unsigned short* __restrict__ nbf,
    const float* __restrict__ w, int add, int nrows)
{
    int wv   = threadIdx.x >> 6;
    int lane = threadIdx.x & 63;
    int row  = blockIdx.x * 4 + wv;
    if (row >= nrows) return;
    const float* hr = hidden + (size_t)row * DM;
    float* rr = residual + (size_t)row * DM;
    float x0 = hr[lane], x1 = hr[lane + 64], x2 = hr[lane + 128];
    if (add) { x0 += rr[lane]; x1 += rr[lane + 64]; x2 += rr[lane + 128]; }
    rr[lane] = x0; rr[lane + 64] = x1; rr[lane + 128] = x2;
    float ss = x0 * x0 + x1 * x1 + x2 * x2;
    #pragma unroll
    for (int off = 32; off > 0; off >>= 1) ss += __shfl_down(ss, off);
    ss = __shfl(ss, 0);
    float scale = rsqrtf(ss / (float)DM + 1e-5f);
    unsigned short* nr = nbf + (size_t)row * DM;
    nr[lane]       = f2bf(x0 * scale * w[lane]);
    nr[lane + 64]  = f2bf(x1 * scale * w[lane + 64]);
    nr[lane + 128] = f2bf(x2 * scale * w[lane + 128]);
}

// ---------------- bf16 MFMA GEMM: C[M,N] = A[M,K] * W[N,K]^T ----------------
// 64x64 tile, 256 threads = 4 waves, each wave a 16-row strip, 4 col-frags.
// act: 0 none, 1 softplus. Optional dual bf16 store to Cbf.
__global__ __launch_bounds__(256) void gemm_bf(
    const unsigned short* __restrict__ A, int lda,
    const unsigned short* __restrict__ W, int ldw,
    float* __restrict__ C, int ldc,
    unsigned short* __restrict__ Cbf, int ldcbf,
    const float* __restrict__ bias,
    int M, int N, int K, int act)
{
    int w    = threadIdx.x >> 6;
    int lane = threadIdx.x & 63;
    int q    = lane >> 4;
    int r    = lane & 15;
    int bm   = blockIdx.y * 64 + w * 16;
    int bn   = blockIdx.x * 64;

    int arow = bm + r; if (arow > M - 1) arow = M - 1;
    int n0 = bn + r;      if (n0 > N - 1) n0 = N - 1;
    int n1 = bn + 16 + r; if (n1 > N - 1) n1 = N - 1;
    int n2 = bn + 32 + r; if (n2 > N - 1) n2 = N - 1;
    int n3 = bn + 48 + r; if (n3 > N - 1) n3 = N - 1;

    const unsigned short* Ap = A + (size_t)arow * lda + q * 8;
    const unsigned short* W0 = W + (size_t)n0 * ldw + q * 8;
    const unsigned short* W1 = W + (size_t)n1 * ldw + q * 8;
    const unsigned short* W2 = W + (size_t)n2 * ldw + q * 8;
    const unsigned short* W3 = W + (size_t)n3 * ldw + q * 8;

    f4 acc0 = {0.f,0.f,0.f,0.f}, acc1 = acc0, acc2 = acc0, acc3 = acc0;

    int kfull = K & ~31;
    for (int k0 = 0; k0 < kfull; k0 += 32) {
        s8b af = *(const s8b*)(Ap + k0);
        s8b b0 = *(const s8b*)(W0 + k0);
        s8b b1 = *(const s8b*)(W1 + k0);
        s8b b2 = *(const s8b*)(W2 + k0);
        s8b b3 = *(const s8b*)(W3 + k0);
        acc0 = __builtin_amdgcn_mfma_f32_16x16x32_bf16(af, b0, acc0, 0, 0, 0);
        acc1 = __builtin_amdgcn_mfma_f32_16x16x32_bf16(af, b1, acc1, 0, 0, 0);
        acc2 = __builtin_amdgcn_mfma_f32_16x16x32_bf16(af, b2, acc2, 0, 0, 0);
        acc3 = __builtin_amdgcn_mfma_f32_16x16x32_bf16(af, b3, acc3, 0, 0, 0);
    }
    if (K & 31) {           // masked tail (dt_proj: K=12)
        int kb = kfull + q * 8;
        s8b zf = {0,0,0,0,0,0,0,0};
        s8b af = zf, b0 = zf, b1 = zf, b2 = zf, b3 = zf;
        if (kb < K) {
            af = *(const s8b*)(Ap + kfull);
            b0 = *(const s8b*)(W0 + kfull);
            b1 = *(const s8b*)(W1 + kfull);
            b2 = *(const s8b*)(W2 + kfull);
            b3 = *(const s8b*)(W3 + kfull);
            #pragma unroll
            for (int j = 0; j < 8; ++j)
                if (kb + j >= K) { af[j] = 0; b0[j] = 0; b1[j] = 0; b2[j] = 0; b3[j] = 0; }
        }
        acc0 = __builtin_amdgcn_mfma_f32_16x16x32_bf16(af, b0, acc0, 0, 0, 0);
        acc1 = __builtin_amdgcn_mfma_f32_16x16x32_bf16(af, b1, acc1, 0, 0, 0);
        acc2 = __builtin_amdgcn_mfma_f32_16x16x32_bf16(af, b2, acc2, 0, 0, 0);
        acc3 = __builtin_amdgcn_mfma_f32_16x16x32_bf16(af, b3, acc3, 0, 0, 0);
    }

    // C/D layout: col = lane&15, row = (lane>>4)*4 + reg
    f4 accs[4] = {acc0, acc1, acc2, acc3};
    #pragma unroll
    for (int c = 0; c < 4; ++c) {
        int gn = bn + c * 16 + r;
        if (gn >= N) continue;
        float bi = bias ? bias[gn] : 0.f;
        #pragma unroll
        for (int reg = 0; reg < 4; ++reg) {
            int gm = bm + q * 4 + reg;
            if (gm >= M) continue;
            float v = accs[c][reg] + bi;
            if (act == 1) v = fmaxf(v, 0.f) + log1pf(expf(-fabsf(v)));
            C[(size_t)gm * ldc + gn] = v;
            if (Cbf) Cbf[(size_t)gm * ldcbf + gn] = f2bf(v);
        }
    }
}

// ---------------- causal depthwise conv (width 4) + silu, dual fp32/bf16 out --------
__global__ __launch_bounds__(256) void conv_silu_kernel(
    const float* __restrict__ xz, const float* __restrict__ cw,
    const float* __restrict__ cb, float* __restrict__ xc,
    unsigned short* __restrict__ xcbf, int total)
{
    int idx = blockIdx.x * 256 + threadIdx.x;
    if (idx >= total) return;
    int d  = idx % DI;
    int bl = idx / DI;
    int l  = bl % L_;
    float acc = cb[d];
    const float* cwd = cw + d * 4;
    #pragma unroll
    for (int k = 0; k < 4; ++k) {
        int ls = l + k - 3;
        if (ls >= 0)
            acc = fmaf(cwd[k], xz[(size_t)(bl - l + ls) * (2 * DI) + d], acc);
    }
    float sig = 1.f / (1.f + __expf(-acc));
    float v = acc * sig;
    xc[idx] = v;
    xcbf[idx] = f2bf(v);
}

// ---------------- selective scan, depth-4 pipelined ----------------
// dt in xz cols [0,384), z in cols [384,768). y -> ybf (bf16).
__global__ __launch_bounds__(64) void scan_kernel(
    const float* __restrict__ xzdt,
    const float* __restrict__ xc,
    const float* __restrict__ dbl,
    const float* __restrict__ A_log,
    const float* __restrict__ Dp,
    unsigned short* __restrict__ ybf)
{
    int b = blockIdx.x / (DI / 64);
    int d = (blockIdx.x % (DI / 64)) * 64 + threadIdx.x;
    float Areg[DSTATE];
    #pragma unroll
    for (int s = 0; s < DSTATE; ++s) Areg[s] = -expf(A_log[d * DSTATE + s]);
    float Dval = Dp[d];
    float h[DSTATE];
    #pragma unroll
    for (int s = 0; s < DSTATE; ++s) h[s] = 0.f;

    size_t base = (size_t)b * L_;
    const float* dtp = xzdt + base * (2 * DI) + d;
    const float* zp  = dtp + DI;
    const float* xcp = xc + base * DI + d;
    const float* bcp = dbl + base * DBLD + DTR;
    unsigned short* yp = ybf + base * DI + d;

    auto ldvec = [&](int l, float& dtv, float& xcv, float& zv) {
        size_t o = (size_t)l * (2 * DI);
        dtv = dtp[o]; zv = zp[o]; xcv = xcp[(size_t)l * DI];
    };
    auto ldbc = [&](int l, float (&bc)[32]) {
        size_t o = (size_t)l * DBLD;
        #pragma unroll
        for (int j = 0; j < 32; ++j) bc[j] = bcp[o + j];
    };
    auto body = [&](float dtv, float xcv, float zv, const float (&bc)[32], int l) {
        float coef = dtv * xcv;
        float y = 0.f;
        #pragma unroll
        for (int s = 0; s < DSTATE; ++s) {
            float dA = __expf(dtv * Areg[s]);
            h[s] = fmaf(h[s], dA, coef * bc[s]);
            y = fmaf(h[s], bc[DSTATE + s], y);
        }
        float yv = fmaf(Dval, xcv, y);
        float sg = 1.f / (1.f + __expf(-zv));
        yp[(size_t)l * DI] = f2bf(yv * (zv * sg));
    };

    float dt0, xc0, z0, dt1, xc1, z1, dt2, xc2, z2, dt3, xc3, z3;
    float bcA[32], bcB[32];
    ldvec(0, dt0, xc0, z0);
    ldvec(1, dt1, xc1, z1);
    ldvec(2, dt2, xc2, z2);
    ldvec(3, dt3, xc3, z3);
    ldbc(0, bcA);
    ldbc(1, bcB);

    for (int l = 0; l < L_; l += 4) {
        body(dt0, xc0, z0, bcA, l);
        if (l + 2 < L_) ldbc(l + 2, bcA);
        if (l + 4 < L_) ldvec(l + 4, dt0, xc0, z0);
        if (l + 1 < L_) {
            body(dt1, xc1, z1, bcB, l + 1);
            if (l + 3 < L_) ldbc(l + 3, bcB);
            if (l + 5 < L_) ldvec(l + 5, dt1, xc1, z1);
        }
        if (l + 2 < L_) {
            body(dt2, xc2, z2, bcA, l + 2);
            if (l + 4 < L_) ldbc(l + 4, bcA);
            if (l + 6 < L_) ldvec(l + 6, dt2, xc2, z2);
        }
        if (l + 3 < L_) {
            body(dt3, xc3, z3, bcB, l + 3);
            if (l + 5 < L_) ldbc(l + 5, bcB);
            if (l + 7 < L_) ldvec(l + 7, dt3, xc3, z3);
        }
    }
}

// ---------------- final rms on cls row only ----------------
__global__ __launch_bounds__(64) void final_kernel(
    const float* __restrict__ hidden, const float* __restrict__ residual,
    const float* __restrict__ wf, float* __restrict__ v_sem)
{
    int b = blockIdx.x;
    int lane = threadIdx.x;
    size_t row = (size_t)b * L_ + 400;
    const float* hr = hidden + row * DM;
    const float* rr = residual + row * DM;
    float x0 = hr[lane] + rr[lane];
    float x1 = hr[lane + 64] + rr[lane + 64];
    float x2 = hr[lane + 128] + rr[lane + 128];
    float ss = x0 * x0 + x1 * x1 + x2 * x2;
    #pragma unroll
    for (int off = 32; off > 0; off >>= 1) ss += __shfl_down(ss, off);
    ss = __shfl(ss, 0);
    float scale = rsqrtf(ss / (float)DM + 1e-5f);
    v_sem[b * DM + lane]       = x0 * scale * wf[lane];
    v_sem[b * DM + lane + 64]  = x1 * scale * wf[lane + 64];
    v_sem[b * DM + lane + 128] = x2 * scale * wf[lane + 128];
}

// ---------------- tiny MLPs + head ----------------
__global__ __launch_bounds__(256) void mlp1_kernel(
    const float* __restrict__ pl, const float* __restrict__ iat,
    const float* __restrict__ w, const float* __restrict__ bias,
    float* __restrict__ out)
{
    int idx = blockIdx.x * 256 + threadIdx.x;
    if (idx >= 128 * 128) return;
    int b = idx / 128, j = idx % 128;
    float acc = bias[j];
    const float* wr = w + j * 200;
    const float* pr = pl + b * 100;
    const float* ir = iat + b * 100;
    for (int k = 0; k < 100; ++k) acc = fmaf(pr[k], wr[k], acc);
    for (int k = 0; k < 100; ++k) acc = fmaf(ir[k], wr[100 + k], acc);
    out[idx] = fmaxf(acc, 0.f);
}

__global__ __launch_bounds__(256) void mlp2_kernel(
    const float* __restrict__ h1, const float* __restrict__ w,
    const float* __restrict__ bias, float* __restrict__ out)
{
    int idx = blockIdx.x * 256 + threadIdx.x;
    if (idx >= 128 * 128) return;
    int b = idx / 128, j = idx % 128;
    float acc = bias[j];
    const float* wr = w + j * 128;
    const float* hr = h1 + b * 128;
    for (int k = 0; k < 128; ++k) acc = fmaf(hr[k], wr[k], acc);
    out[idx] = acc;
}

__global__ __launch_bounds__(256) void head_kernel(
    const float* __restrict__ v_sem, const float* __restrict__ v_stat,
    const float* __restrict__ w, const float* __restrict__ bias,
    float* __restrict__ out)
{
    int idx = blockIdx.x * 256 + threadIdx.x;
    if (idx >= 128 * 20) return;
    int b = idx / 20, o = idx % 20;
    float acc = bias[o];
    const float* wr = w + o * 320;
    const float* vs = v_sem + b * DM;
    const float* vt = v_stat + b * 128;
    for (int k = 0; k < DM; ++k)  acc = fmaf(vs[k], wr[k], acc);
    for (int k = 0; k < 128; ++k) acc = fmaf(vt[k], wr[DM + k], acc);
    out[idx] = acc;
}

extern "C" void kernel_launch(void* const* d_in, const int* in_sizes, int n_in,
                              void* d_out, int out_size, void* d_ws, size_t ws_size,
                              hipStream_t stream)
{
    const float* imgs       = (const float*)d_in[0];
    const float* pl         = (const float*)d_in[1];
    const float* iat        = (const float*)d_in[2];
    const float* pe_w       = (const float*)d_in[3];
    const float* pe_b       = (const float*)d_in[4];
    const float* cls_token  = (const float*)d_in[5];
    const float* pos_embed  = (const float*)d_in[6];
    const float* norm_ws    = (const float*)d_in[7];
    const float* in_proj_ws = (const float*)d_in[8];
    const float* conv_ws    = (const float*)d_in[9];
    const float* conv_bs    = (const float*)d_in[10];
    const float* x_proj_ws  = (const float*)d_in[11];
    const float* dt_proj_ws = (const float*)d_in[12];
    const float* dt_proj_bs = (const float*)d_in[13];
    const float* A_logs     = (const float*)d_in[14];
    const float* Ds         = (const float*)d_in[15];
    const float* out_proj_ws= (const float*)d_in[16];
    const float* norm_f_w   = (const float*)d_in[17];
    const float* mlp1_w     = (const float*)d_in[18];
    const float* mlp1_b     = (const float*)d_in[19];
    const float* mlp2_w     = (const float*)d_in[20];
    const float* mlp2_b     = (const float*)d_in[21];
    const float* head_w     = (const float*)d_in[22];
    const float* head_b     = (const float*)d_in[23];

    float* ws = (float*)d_ws;
    size_t off = 0;
    float* v_sem  = ws + off; off += 128 * DM;
    float* h1     = ws + off; off += 128 * 128;
    float* v_stat = ws + off; off += 128 * 128;
    // bf16 weight arenas (ushort counts halved into float units, all mult of 8)
    unsigned short* inw_bf = (unsigned short*)(ws + off); off += (size_t)4 * 768 * DM / 2;
    unsigned short* xpw_bf = (unsigned short*)(ws + off); off += (size_t)4 * 44 * DI / 2;
    unsigned short* dtw_bf = (unsigned short*)(ws + off); off += (size_t)4 * DI * 16 / 2;
    unsigned short* ow_bf  = (unsigned short*)(ws + off); off += (size_t)4 * DM * DI / 2;
    float* chunkbuf = ws + off;
    size_t small_floats = off;

    // per-row floats: hidden 192 + residual 192 + xz 768 + xc 384 + dbl 48
    //               + nbf 96 + xybf 192 + dblbf 24  = 1896
    const size_t per_row = 192 + 192 + 768 + 384 + DBLD + 96 + 192 + 24;
    size_t avail = ws_size / sizeof(float);
    avail = (avail > small_floats) ? (avail - small_floats) : 0;
    int Bc = (int)(avail / (per_row * (size_t)L_));
    if (Bc > B_) Bc = B_;
    if (Bc < 1) Bc = 1;

    // weight conversion (once per call; ws is re-poisoned each timed call)
    convw_kernel<<<512, 256, 0, stream>>>(in_proj_ws, inw_bf, 4 * 768, DM, DM);
    convw_kernel<<<128, 256, 0, stream>>>(x_proj_ws, xpw_bf, 4 * 44, DI, DI);
    convw_kernel<<<64,  256, 0, stream>>>(dt_proj_ws, dtw_bf, 4 * DI, DTR, 16);
    convw_kernel<<<512, 256, 0, stream>>>(out_proj_ws, ow_bf, 4 * DM, DI, DI);

    for (int b0 = 0; b0 < B_; b0 += Bc) {
        int bc = (B_ - b0 < Bc) ? (B_ - b0) : Bc;
        int rows = bc * L_;
        float* hidden   = chunkbuf;
        float* residual = hidden + (size_t)rows * DM;
        float* xz       = residual + (size_t)rows * DM;          // [rows][768]
        float* xc       = xz + (size_t)rows * 2 * DI;
        float* dbl      = xc + (size_t)rows * DI;                // ld DBLD
        unsigned short* nbf   = (unsigned short*)(dbl + (size_t)rows * DBLD);
        unsigned short* xybf  = nbf + (size_t)rows * DM;         // xc_bf then y_bf, ld 384
        unsigned short* dblbf = xybf + (size_t)rows * DI;        // ld 48

        int gmy = (rows + 63) / 64;

        embed_kernel<<<rows, DM, 0, stream>>>(imgs + (size_t)b0 * 1600,
                                              pe_w, pe_b, cls_token, pos_embed, hidden);

        for (int i = 0; i < 4; ++i) {
            rms_kernel<<<(rows + 3) / 4, 256, 0, stream>>>(
                hidden, residual, nbf, norm_ws + i * DM, i > 0 ? 1 : 0, rows);
            // in_proj: (rows,192)x(768,192)^T -> xz fp32
            gemm_bf<<<dim3(12, gmy), 256, 0, stream>>>(
                nbf, DM, inw_bf + (size_t)i * 768 * DM, DM,
                xz, 2 * DI, nullptr, 0, nullptr, rows, 2 * DI, DM, 0);
            // conv + silu -> xc fp32 + xybf bf16
            int convTot = rows * DI;
            conv_silu_kernel<<<(convTot + 255) / 256, 256, 0, stream>>>(
                xz, conv_ws + i * DI * 4, conv_bs + i * DI, xc, xybf, convTot);
            // x_proj: (rows,384)x(44,384)^T -> dbl fp32 (ld 48) + dblbf bf16 (ld 48)
            gemm_bf<<<dim3(1, gmy), 256, 0, stream>>>(
                xybf, DI, xpw_bf + (size_t)i * 44 * DI, DI,
                dbl, DBLD, dblbf, DBLD, nullptr, rows, 44, DI, 0);
            // dt_proj: (rows,12)x(384,12)^T + bias -> softplus -> xz cols [0,384)
            gemm_bf<<<dim3(6, gmy), 256, 0, stream>>>(
                dblbf, DBLD, dtw_bf + (size_t)i * DI * 16, 16,
                xz, 2 * DI, nullptr, 0, dt_proj_bs + i * DI, rows, DI, DTR, 1);
            // scan -> xybf (bf16 y)
            scan_kernel<<<bc * (DI / 64), 64, 0, stream>>>(
                xz, xc, dbl, A_logs + (size_t)i * DI * DSTATE, Ds + i * DI, xybf);
            // out_proj: (rows,384)x(192,384)^T -> hidden fp32
            gemm_bf<<<dim3(3, gmy), 256, 0, stream>>>(
                xybf, DI, ow_bf + (size_t)i * DM * DI, DI,
                hidden, DM, nullptr, 0, nullptr, rows, DM, DI, 0);
        }

        final_kernel<<<bc, 64, 0, stream>>>(hidden, residual, norm_f_w,
                                            v_sem + (size_t)b0 * DM);
    }

    mlp1_kernel<<<64, 256, 0, stream>>>(pl, iat, mlp1_w, mlp1_b, h1);
    mlp2_kernel<<<64, 256, 0, stream>>>(h1, mlp2_w, mlp2_b, v_stat);
    head_kernel<<<10, 256, 0, stream>>>(v_sem, v_stat, head_w, head_b, (float*)d_out);
}

// Round 4
// 3176.330 us; speedup vs baseline: 1.8125x; 1.0902x over previous
//
#include <hip/hip_runtime.h>
#include <math.h>

#define B_   128
#define L_   401
#define DM   192
#define DI   384
#define DSTATE 16
#define DTR  12
#define SEG  8
#define SEGLEN 51    // ceil(401/8); segments 0..6 full 51, segment 7 = 44

typedef __attribute__((ext_vector_type(8))) short s8b;     // 8 bf16
typedef __attribute__((ext_vector_type(4))) float f4;
typedef __attribute__((ext_vector_type(16))) float f16v;

__device__ __forceinline__ unsigned short f2bf(float x) {
    unsigned int u = __builtin_bit_cast(unsigned int, x);
    unsigned int r = (u + 0x7fffu + ((u >> 16) & 1u)) >> 16;
    return (unsigned short)r;
}
__device__ __forceinline__ float bf2f(unsigned short x) {
    unsigned int u = ((unsigned int)x) << 16;
    return __builtin_bit_cast(float, u);
}

// ---------------- weight fp32 -> bf16 ----------------
__global__ __launch_bounds__(256) void convw_kernel(
    const float* __restrict__ src, unsigned short* __restrict__ dst, int total)
{
    for (int idx = blockIdx.x * 256 + threadIdx.x; idx < total; idx += gridDim.x * 256)
        dst[idx] = f2bf(src[idx]);
}

// ---------------- build fused x_proj+dt_proj weight: [4][416][384] bf16 --------
// rows 0..383:  W_comb[d,k] = sum_r dt_w[d,r]*xp_w[r,k]   (dt path)
// rows 384..415: xp_w[12+c, k]                            (B,C path)
__global__ __launch_bounds__(256) void build_xdtw_kernel(
    const float* __restrict__ xp_w, const float* __restrict__ dt_w,
    unsigned short* __restrict__ out)
{
    int idx = blockIdx.x * 256 + threadIdx.x;
    if (idx >= 4 * 416 * 384) return;
    int k  = idx % 384;
    int rr = (idx / 384) % 416;
    int i  = idx / (384 * 416);
    const float* xp = xp_w + (size_t)i * 44 * 384;
    float v;
    if (rr < 384) {
        const float* dw = dt_w + (size_t)i * 384 * 12 + rr * 12;
        v = 0.f;
        #pragma unroll
        for (int r = 0; r < 12; ++r) v = fmaf(dw[r], xp[r * 384 + k], v);
    } else {
        v = xp[(12 + (rr - 384)) * 384 + k];
    }
    out[idx] = f2bf(v);
}

// ---------------- embed ----------------
__global__ void embed_kernel(const float* __restrict__ imgs,
                             const float* __restrict__ pe_w,
                             const float* __restrict__ pe_b,
                             const float* __restrict__ cls_token,
                             const float* __restrict__ pos_embed,
                             float* __restrict__ x)
{
    int row = blockIdx.x;
    int l = row % L_;
    int b = row / L_;
    int d = threadIdx.x;
    float v;
    if (l < 400) {
        const float* f = imgs + (size_t)b * 1600 + (size_t)l * 4;
        const float* pw = pe_w + d * 4;
        v = pe_b[d];
        v = fmaf(f[0], pw[0], v);
        v = fmaf(f[1], pw[1], v);
        v = fmaf(f[2], pw[2], v);
        v = fmaf(f[3], pw[3], v);
        v += pos_embed[l * DM + d];
    } else {
        v = cls_token[d] + pos_embed[400 * DM + d];
    }
    x[(size_t)row * DM + d] = v;
}

// ---------------- rms norm (+residual), bf16 normed output ----------------
__global__ __launch_bounds__(256) void rms_kernel(
    const float* hidden, float* residual, unsigned short* __restrict__ nbf,
    const float* __restrict__ w, int add, int nrows)
{
    int wv   = threadIdx.x >> 6;
    int lane = threadIdx.x & 63;
    int row  = blockIdx.x * 4 + wv;
    if (row >= nrows) return;
    const float* hr = hidden + (size_t)row * DM;
    float* rr = residual + (size_t)row * DM;
    float x0 = hr[lane], x1 = hr[lane + 64], x2 = hr[lane + 128];
    if (add) { x0 += rr[lane]; x1 += rr[lane + 64]; x2 += rr[lane + 128]; }
    rr[lane] = x0; rr[lane + 64] = x1; rr[lane + 128] = x2;
    float ss = x0 * x0 + x1 * x1 + x2 * x2;
    #pragma unroll
    for (int off = 32; off > 0; off >>= 1) ss += __shfl_down(ss, off);
    ss = __shfl(ss, 0);
    float scale = rsqrtf(ss / (float)DM + 1e-5f);
    unsigned short* nr = nbf + (size_t)row * DM;
    nr[lane]       = f2bf(x0 * scale * w[lane]);
    nr[lane + 64]  = f2bf(x1 * scale * w[lane + 64]);
    nr[lane + 128] = f2bf(x2 * scale * w[lane + 128]);
}

// ---------------- bf16 MFMA GEMM: C[M,N] = A[M,K]*W[N,K]^T, K%32==0 ----------------
// Outputs: C fp32 (opt), Cbf bf16 (opt). If splitN>0: cols >= splitN go raw to C2.
__global__ __launch_bounds__(256) void gemm_bf(
    const unsigned short* __restrict__ A, int lda,
    const unsigned short* __restrict__ W, int ldw,
    float* __restrict__ C, int ldc,
    unsigned short* __restrict__ Cbf, int ldcbf,
    float* __restrict__ C2, int ldc2, int splitN,
    const float* __restrict__ bias,
    int M, int N, int K, int act)
{
    int w    = threadIdx.x >> 6;
    int lane = threadIdx.x & 63;
    int q    = lane >> 4;
    int r    = lane & 15;
    int bm   = blockIdx.y * 64 + w * 16;
    int bn   = blockIdx.x * 64;

    int arow = bm + r; if (arow > M - 1) arow = M - 1;
    int n0 = bn + r;      if (n0 > N - 1) n0 = N - 1;
    int n1 = bn + 16 + r; if (n1 > N - 1) n1 = N - 1;
    int n2 = bn + 32 + r; if (n2 > N - 1) n2 = N - 1;
    int n3 = bn + 48 + r; if (n3 > N - 1) n3 = N - 1;

    const unsigned short* Ap = A + (size_t)arow * lda + q * 8;
    const unsigned short* W0 = W + (size_t)n0 * ldw + q * 8;
    const unsigned short* W1 = W + (size_t)n1 * ldw + q * 8;
    const unsigned short* W2 = W + (size_t)n2 * ldw + q * 8;
    const unsigned short* W3 = W + (size_t)n3 * ldw + q * 8;

    f4 acc0 = {0.f,0.f,0.f,0.f}, acc1 = acc0, acc2 = acc0, acc3 = acc0;

    for (int k0 = 0; k0 < K; k0 += 32) {
        s8b af = *(const s8b*)(Ap + k0);
        s8b b0 = *(const s8b*)(W0 + k0);
        s8b b1 = *(const s8b*)(W1 + k0);
        s8b b2 = *(const s8b*)(W2 + k0);
        s8b b3 = *(const s8b*)(W3 + k0);
        acc0 = __builtin_amdgcn_mfma_f32_16x16x32_bf16(af, b0, acc0, 0, 0, 0);
        acc1 = __builtin_amdgcn_mfma_f32_16x16x32_bf16(af, b1, acc1, 0, 0, 0);
        acc2 = __builtin_amdgcn_mfma_f32_16x16x32_bf16(af, b2, acc2, 0, 0, 0);
        acc3 = __builtin_amdgcn_mfma_f32_16x16x32_bf16(af, b3, acc3, 0, 0, 0);
    }

    // C/D layout: col = lane&15, row = (lane>>4)*4 + reg
    f4 accs[4] = {acc0, acc1, acc2, acc3};
    #pragma unroll
    for (int c = 0; c < 4; ++c) {
        int gn = bn + c * 16 + r;
        if (gn >= N) continue;
        #pragma unroll
        for (int reg = 0; reg < 4; ++reg) {
            int gm = bm + q * 4 + reg;
            if (gm >= M) continue;
            float v = accs[c][reg];
            if (splitN > 0 && gn >= splitN) {
                C2[(size_t)gm * ldc2 + (gn - splitN)] = v;
            } else {
                if (bias) v += bias[gn];
                if (act == 1) v = fmaxf(v, 0.f) + log1pf(expf(-fabsf(v)));
                if (C)   C[(size_t)gm * ldc + gn] = v;
                if (Cbf) Cbf[(size_t)gm * ldcbf + gn] = f2bf(v);
            }
        }
    }
}

// ---------------- causal depthwise conv (width 4) + silu, bf16 in/out --------
__global__ __launch_bounds__(256) void conv_silu_kernel(
    const unsigned short* __restrict__ xzbf, const float* __restrict__ cw,
    const float* __restrict__ cb, unsigned short* __restrict__ xcbf, int total)
{
    int idx = blockIdx.x * 256 + threadIdx.x;
    if (idx >= total) return;
    int d  = idx % DI;
    int bl = idx / DI;
    int l  = bl % L_;
    float acc = cb[d];
    const float* cwd = cw + d * 4;
    #pragma unroll
    for (int k = 0; k < 4; ++k) {
        int ls = l + k - 3;
        if (ls >= 0)
            acc = fmaf(cwd[k], bf2f(xzbf[(size_t)(bl - l + ls) * (2 * DI) + d]), acc);
    }
    float sig = 1.f / (1.f + __expf(-acc));
    xcbf[idx] = f2bf(acc * sig);
}

// ---------------- scan pass 1: per-segment transition (P, h_local) ----------------
// grid: bc*6*7 blocks of 64; blockIdx.x = (b*6+dblk)*7 + j, j in 0..6 (all len 51)
__global__ __launch_bounds__(64) void scan1_kernel(
    const float* __restrict__ dt,
    const unsigned short* __restrict__ xcbf,
    const float* __restrict__ dbl,
    const float* __restrict__ A_log,
    float* __restrict__ Hbuf)
{
    int j = blockIdx.x % 7;
    int t = blockIdx.x / 7;
    int b = t / 6;
    int d = (t % 6) * 64 + threadIdx.x;
    f16v Av, hv, Pv;
    #pragma unroll
    for (int s = 0; s < 16; ++s) { Av[s] = -expf(A_log[d * 16 + s]); hv[s] = 0.f; Pv[s] = 1.f; }

    size_t base = (size_t)b * L_;
    const float* dtp = dt + base * DI + d;
    const unsigned short* xcp = xcbf + base * DI + d;
    const float* bp = dbl + base * 32;
    int l0 = j * SEGLEN;
    int lend = l0 + SEGLEN;

    float dtv[4], xcv[4];
    #pragma unroll
    for (int i = 0; i < 4; ++i) {
        dtv[i] = dtp[(size_t)(l0 + i) * DI];
        xcv[i] = bf2f(xcp[(size_t)(l0 + i) * DI]);
    }
    f16v B0, B1;
    #pragma unroll
    for (int s2 = 0; s2 < 16; ++s2) { B0[s2] = bp[(size_t)l0 * 32 + s2]; B1[s2] = bp[(size_t)(l0 + 1) * 32 + s2]; }

#define S1_BODY(dt_, xc_, Bv)                                            \
    { float coef = (dt_) * (xc_);                                        \
      _Pragma("unroll")                                                  \
      for (int s = 0; s < 16; ++s) {                                     \
          float dA = __expf((dt_) * Av[s]);                              \
          hv[s] = fmaf(hv[s], dA, coef * Bv[s]);                         \
          Pv[s] *= dA; } }
#define S1_PF_B(Bv, lq)                                                  \
    if ((lq) < lend) { _Pragma("unroll")                                 \
      for (int s2 = 0; s2 < 16; ++s2) Bv[s2] = bp[(size_t)(lq) * 32 + s2]; }
#define S1_PF_S(i_, lq)                                                  \
    if ((lq) < lend) { dtv[i_] = dtp[(size_t)(lq) * DI];                 \
      xcv[i_] = bf2f(xcp[(size_t)(lq) * DI]); }

    for (int l = l0; l < lend; l += 4) {
        S1_BODY(dtv[0], xcv[0], B0); S1_PF_B(B0, l + 2); S1_PF_S(0, l + 4);
        if (l + 1 < lend) { S1_BODY(dtv[1], xcv[1], B1); S1_PF_B(B1, l + 3); S1_PF_S(1, l + 5); }
        if (l + 2 < lend) { S1_BODY(dtv[2], xcv[2], B0); S1_PF_B(B0, l + 4); S1_PF_S(2, l + 6); }
        if (l + 3 < lend) { S1_BODY(dtv[3], xcv[3], B1); S1_PF_B(B1, l + 5); S1_PF_S(3, l + 7); }
    }
    float* Hp = Hbuf + (size_t)blockIdx.x * 2048 + threadIdx.x;
    #pragma unroll
    for (int s = 0; s < 16; ++s) { Hp[s * 64] = Pv[s]; Hp[(16 + s) * 64] = hv[s]; }
}

// ---------------- scan pass 2: compose h_start, scan segment, emit y ----------------
// grid: bc*6*8 blocks of 64; blockIdx.x = (b*6+dblk)*8 + j
__global__ __launch_bounds__(64) void scan2_kernel(
    const float* __restrict__ dt,
    const unsigned short* __restrict__ xcbf,
    const unsigned short* __restrict__ xzbf,
    const float* __restrict__ dbl,
    const float* __restrict__ A_log,
    const float* __restrict__ Dp,
    const float* __restrict__ Hbuf,
    unsigned short* __restrict__ ybf)
{
    int j = blockIdx.x & 7;
    int t = blockIdx.x >> 3;
    int b = t / 6;
    int d = (t % 6) * 64 + threadIdx.x;
    f16v Av, hv;
    #pragma unroll
    for (int s = 0; s < 16; ++s) { Av[s] = -expf(A_log[d * 16 + s]); hv[s] = 0.f; }
    float Dval = Dp[d];

    const float* Hp = Hbuf + (size_t)t * 7 * 2048 + threadIdx.x;
    for (int k = 0; k < j; ++k) {
        const float* hp = Hp + (size_t)k * 2048;
        #pragma unroll
        for (int s = 0; s < 16; ++s)
            hv[s] = fmaf(hp[s * 64], hv[s], hp[(16 + s) * 64]);
    }

    size_t base = (size_t)b * L_;
    const float* dtp = dt + base * DI + d;
    const unsigned short* xcp = xcbf + base * DI + d;
    const unsigned short* zp  = xzbf + base * (2 * DI) + DI + d;
    const float* bcp = dbl + base * 32;
    unsigned short* yp = ybf + base * DI + d;
    int l0 = j * SEGLEN;
    int lend = l0 + SEGLEN; if (lend > L_) lend = L_;

    float dtv[4], xcv[4], zv[4];
    #pragma unroll
    for (int i = 0; i < 4; ++i) {            // all segments >= 44 long
        dtv[i] = dtp[(size_t)(l0 + i) * DI];
        xcv[i] = bf2f(xcp[(size_t)(l0 + i) * DI]);
        zv[i]  = bf2f(zp[(size_t)(l0 + i) * (2 * DI)]);
    }
    f16v B0, C0, B1, C1;
    #pragma unroll
    for (int s2 = 0; s2 < 16; ++s2) {
        B0[s2] = bcp[(size_t)l0 * 32 + s2];       C0[s2] = bcp[(size_t)l0 * 32 + 16 + s2];
        B1[s2] = bcp[(size_t)(l0 + 1) * 32 + s2]; C1[s2] = bcp[(size_t)(l0 + 1) * 32 + 16 + s2];
    }

#define S2_BODY(dt_, xc_, z_, Bv, Cv, lcur)                              \
    { float coef = (dt_) * (xc_); float y = 0.f;                         \
      _Pragma("unroll")                                                  \
      for (int s = 0; s < 16; ++s) {                                     \
          float dA = __expf((dt_) * Av[s]);                              \
          hv[s] = fmaf(hv[s], dA, coef * Bv[s]);                         \
          y = fmaf(hv[s], Cv[s], y); }                                   \
      float yv = fmaf(Dval, (xc_), y);                                   \
      float sg = 1.f / (1.f + __expf(-(z_)));                            \
      yp[(size_t)(lcur) * DI] = f2bf(yv * ((z_) * sg)); }
#define S2_PF_BC(Bv, Cv, lq)                                             \
    if ((lq) < lend) { _Pragma("unroll")                                 \
      for (int s2 = 0; s2 < 16; ++s2) {                                  \
          Bv[s2] = bcp[(size_t)(lq) * 32 + s2];                          \
          Cv[s2] = bcp[(size_t)(lq) * 32 + 16 + s2]; } }
#define S2_PF_S(i_, lq)                                                  \
    if ((lq) < lend) { dtv[i_] = dtp[(size_t)(lq) * DI];                 \
      xcv[i_] = bf2f(xcp[(size_t)(lq) * DI]);                            \
      zv[i_]  = bf2f(zp[(size_t)(lq) * (2 * DI)]); }

    for (int l = l0; l < lend; l += 4) {
        S2_BODY(dtv[0], xcv[0], zv[0], B0, C0, l); S2_PF_BC(B0, C0, l + 2); S2_PF_S(0, l + 4);
        if (l + 1 < lend) { S2_BODY(dtv[1], xcv[1], zv[1], B1, C1, l + 1); S2_PF_BC(B1, C1, l + 3); S2_PF_S(1, l + 5); }
        if (l + 2 < lend) { S2_BODY(dtv[2], xcv[2], zv[2], B0, C0, l + 2); S2_PF_BC(B0, C0, l + 4); S2_PF_S(2, l + 6); }
        if (l + 3 < lend) { S2_BODY(dtv[3], xcv[3], zv[3], B1, C1, l + 3); S2_PF_BC(B1, C1, l + 5); S2_PF_S(3, l + 7); }
    }
}

// ---------------- final rms on cls row only ----------------
__global__ __launch_bounds__(64) void final_kernel(
    const float* __restrict__ hidden, const float* __restrict__ residual,
    const float* __restrict__ wf, float* __restrict__ v_sem)
{
    int b = blockIdx.x;
    int lane = threadIdx.x;
    size_t row = (size_t)b * L_ + 400;
    const float* hr = hidden + row * DM;
    const float* rr = residual + row * DM;
    float x0 = hr[lane] + rr[lane];
    float x1 = hr[lane + 64] + rr[lane + 64];
    float x2 = hr[lane + 128] + rr[lane + 128];
    float ss = x0 * x0 + x1 * x1 + x2 * x2;
    #pragma unroll
    for (int off = 32; off > 0; off >>= 1) ss += __shfl_down(ss, off);
    ss = __shfl(ss, 0);
    float scale = rsqrtf(ss / (float)DM + 1e-5f);
    v_sem[b * DM + lane]       = x0 * scale * wf[lane];
    v_sem[b * DM + lane + 64]  = x1 * scale * wf[lane + 64];
    v_sem[b * DM + lane + 128] = x2 * scale * wf[lane + 128];
}

// ---------------- tiny MLPs + head ----------------
__global__ __launch_bounds__(256) void mlp1_kernel(
    const float* __restrict__ pl, const float* __restrict__ iat,
    const float* __restrict__ w, const float* __restrict__ bias,
    float* __restrict__ out)
{
    int idx = blockIdx.x * 256 + threadIdx.x;
    if (idx >= 128 * 128) return;
    int b = idx / 128, j = idx % 128;
    float acc = bias[j];
    const float* wr = w + j * 200;
    const float* pr = pl + b * 100;
    const float* ir = iat + b * 100;
    for (int k = 0; k < 100; ++k) acc = fmaf(pr[k], wr[k], acc);
    for (int k = 0; k < 100; ++k) acc = fmaf(ir[k], wr[100 + k], acc);
    out[idx] = fmaxf(acc, 0.f);
}

__global__ __launch_bounds__(256) void mlp2_kernel(
    const float* __restrict__ h1, const float* __restrict__ w,
    const float* __restrict__ bias, float* __restrict__ out)
{
    int idx = blockIdx.x * 256 + threadIdx.x;
    if (idx >= 128 * 128) return;
    int b = idx / 128, j = idx % 128;
    float acc = bias[j];
    const float* wr = w + j * 128;
    const float* hr = h1 + b * 128;
    for (int k = 0; k < 128; ++k) acc = fmaf(hr[k], wr[k], acc);
    out[idx] = acc;
}

__global__ __launch_bounds__(256) void head_kernel(
    const float* __restrict__ v_sem, const float* __restrict__ v_stat,
    const float* __restrict__ w, const float* __restrict__ bias,
    float* __restrict__ out)
{
    int idx = blockIdx.x * 256 + threadIdx.x;
    if (idx >= 128 * 20) return;
    int b = idx / 20, o = idx % 20;
    float acc = bias[o];
    const float* wr = w + o * 320;
    const float* vs = v_sem + b * DM;
    const float* vt = v_stat + b * 128;
    for (int k = 0; k < DM; ++k)  acc = fmaf(vs[k], wr[k], acc);
    for (int k = 0; k < 128; ++k) acc = fmaf(vt[k], wr[DM + k], acc);
    out[idx] = acc;
}

extern "C" void kernel_launch(void* const* d_in, const int* in_sizes, int n_in,
                              void* d_out, int out_size, void* d_ws, size_t ws_size,
                              hipStream_t stream)
{
    const float* imgs       = (const float*)d_in[0];
    const float* pl         = (const float*)d_in[1];
    const float* iat        = (const float*)d_in[2];
    const float* pe_w       = (const float*)d_in[3];
    const float* pe_b       = (const float*)d_in[4];
    const float* cls_token  = (const float*)d_in[5];
    const float* pos_embed  = (const float*)d_in[6];
    const float* norm_ws    = (const float*)d_in[7];
    const float* in_proj_ws = (const float*)d_in[8];
    const float* conv_ws    = (const float*)d_in[9];
    const float* conv_bs    = (const float*)d_in[10];
    const float* x_proj_ws  = (const float*)d_in[11];
    const float* dt_proj_ws = (const float*)d_in[12];
    const float* dt_proj_bs = (const float*)d_in[13];
    const float* A_logs     = (const float*)d_in[14];
    const float* Ds         = (const float*)d_in[15];
    const float* out_proj_ws= (const float*)d_in[16];
    const float* norm_f_w   = (const float*)d_in[17];
    const float* mlp1_w     = (const float*)d_in[18];
    const float* mlp1_b     = (const float*)d_in[19];
    const float* mlp2_w     = (const float*)d_in[20];
    const float* mlp2_b     = (const float*)d_in[21];
    const float* head_w     = (const float*)d_in[22];
    const float* head_b     = (const float*)d_in[23];

    float* ws = (float*)d_ws;
    size_t off = 0;
    float* v_sem  = ws + off; off += 128 * DM;
    float* h1     = ws + off; off += 128 * 128;
    float* v_stat = ws + off; off += 128 * 128;
    unsigned short* inw_bf = (unsigned short*)(ws + off); off += (size_t)4 * 768 * DM / 2;   // 294912 f
    unsigned short* ow_bf  = (unsigned short*)(ws + off); off += (size_t)4 * DM * DI / 2;    // 147456 f
    unsigned short* xdtw   = (unsigned short*)(ws + off); off += (size_t)4 * 416 * DI / 2;   // 319488 f
    float* chunkbuf = ws + off;
    size_t small_floats = off;

    // per-b floats: rows(401) * [hidden 192 + residual 192 + nbf 96 + xzbf 384 +
    //   xcbf 192 + dt 384 + dbl 32 + ybf 192] + Hbuf 6*7*2048
    const size_t per_b = (size_t)L_ * (192 + 192 + 96 + 384 + 192 + 384 + 32 + 192)
                       + (size_t)6 * 7 * 2048;
    size_t avail = ws_size / sizeof(float);
    avail = (avail > small_floats) ? (avail - small_floats) : 0;
    int Bc = (int)(avail / per_b);
    if (Bc > B_) Bc = B_;
    if (Bc < 1) Bc = 1;

    // weight prep (once per call; ws re-poisoned before every timed call)
    convw_kernel<<<512, 256, 0, stream>>>(in_proj_ws, inw_bf, 4 * 768 * DM);
    convw_kernel<<<512, 256, 0, stream>>>(out_proj_ws, ow_bf, 4 * DM * DI);
    build_xdtw_kernel<<<(4 * 416 * 384 + 255) / 256, 256, 0, stream>>>(x_proj_ws, dt_proj_ws, xdtw);

    for (int b0 = 0; b0 < B_; b0 += Bc) {
        int bc = (B_ - b0 < Bc) ? (B_ - b0) : Bc;
        int rows = bc * L_;
        float* hidden   = chunkbuf;
        float* residual = hidden + (size_t)rows * DM;
        float* dtb      = residual + (size_t)rows * DM;            // fp32 dt [rows][384]
        float* dbl      = dtb + (size_t)rows * DI;                 // fp32 B,C [rows][32]
        float* Hbuf     = dbl + (size_t)rows * 32;                 // bc*6*7*2048
        unsigned short* nbf  = (unsigned short*)(Hbuf + (size_t)bc * 6 * 7 * 2048);
        unsigned short* xzbf = nbf + (size_t)rows * DM;            // [rows][768]
        unsigned short* xcbf = xzbf + (size_t)rows * 2 * DI;       // [rows][384]
        unsigned short* ybf  = xcbf + (size_t)rows * DI;           // [rows][384]

        int gmy = (rows + 63) / 64;

        embed_kernel<<<rows, DM, 0, stream>>>(imgs + (size_t)b0 * 1600,
                                              pe_w, pe_b, cls_token, pos_embed, hidden);

        for (int i = 0; i < 4; ++i) {
            rms_kernel<<<(rows + 3) / 4, 256, 0, stream>>>(
                hidden, residual, nbf, norm_ws + i * DM, i > 0 ? 1 : 0, rows);
            // in_proj -> xzbf (bf16 only): (rows,192)x(768,192)^T
            gemm_bf<<<dim3(12, gmy), 256, 0, stream>>>(
                nbf, DM, inw_bf + (size_t)i * 768 * DM, DM,
                nullptr, 0, xzbf, 2 * DI, nullptr, 0, 0,
                nullptr, rows, 2 * DI, DM, 0);
            // conv + silu -> xcbf
            int convTot = rows * DI;
            conv_silu_kernel<<<(convTot + 255) / 256, 256, 0, stream>>>(
                xzbf, conv_ws + i * DI * 4, conv_bs + i * DI, xcbf, convTot);
            // fused x_proj+dt_proj: (rows,384)x(416,384)^T; cols<384 -> softplus dt fp32,
            // cols>=384 -> B,C raw fp32 (ld 32)
            gemm_bf<<<dim3(7, gmy), 256, 0, stream>>>(
                xcbf, DI, xdtw + (size_t)i * 416 * DI, DI,
                dtb, DI, nullptr, 0, dbl, 32, DI,
                dt_proj_bs + i * DI, rows, 416, DI, 1);
            // segmented scan
            scan1_kernel<<<bc * 6 * 7, 64, 0, stream>>>(
                dtb, xcbf, dbl, A_logs + (size_t)i * DI * DSTATE, Hbuf);
            scan2_kernel<<<bc * 6 * 8, 64, 0, stream>>>(
                dtb, xcbf, xzbf, dbl, A_logs + (size_t)i * DI * DSTATE,
                Ds + i * DI, Hbuf, ybf);
            // out_proj: (rows,384)x(192,384)^T -> hidden fp32
            gemm_bf<<<dim3(3, gmy), 256, 0, stream>>>(
                ybf, DI, ow_bf + (size_t)i * DM * DI, DI,
                hidden, DM, nullptr, 0, nullptr, 0, 0,
                nullptr, rows, DM, DI, 0);
        }

        final_kernel<<<bc, 64, 0, stream>>>(hidden, residual, norm_f_w,
                                            v_sem + (size_t)b0 * DM);
    }

    mlp1_kernel<<<64, 256, 0, stream>>>(pl, iat, mlp1_w, mlp1_b, h1);
    mlp2_kernel<<<64, 256, 0, stream>>>(h1, mlp2_w, mlp2_b, v_stat);
    head_kernel<<<10, 256, 0, stream>>>(v_sem, v_stat, head_w, head_b, (float*)d_out);
}